// Round 4
// baseline (185.309 us; speedup 1.0000x reference)
//
#include <hip/hip_runtime.h>
#include <cstdint>

#define B_ 16
#define C_ 1024
#define Q_ 128
#define H_ 768
#define OSTR (4 * H_)  // 3072

typedef __attribute__((ext_vector_type(8))) short bf16x8;
typedef __attribute__((ext_vector_type(4))) float f32x4;
typedef __attribute__((ext_vector_type(4))) int int4v;

__device__ __forceinline__ unsigned short f2bf(float x) {
  union { float f; unsigned u; } v; v.f = x;
  unsigned r = v.u + 0x7FFFu + ((v.u >> 16) & 1u);
  return (unsigned short)(r >> 16);
}
__device__ __forceinline__ unsigned pk2(float a, float b) {
  return (unsigned)f2bf(a) | ((unsigned)f2bf(b) << 16);
}

// two-segment fp32 -> bf16 (Wc, Wq)
__global__ __launch_bounds__(256) void f2bf2_kernel(
    const float* __restrict__ s0, unsigned short* __restrict__ d0, int n0,
    const float* __restrict__ s1, unsigned short* __restrict__ d1, int n1) {
  int i = blockIdx.x * 256 + threadIdx.x;
  const float* s;
  unsigned short* d;
  if (i < n0) { s = s0; d = d0; }
  else if (i < n0 + n1) { s = s1; d = d1; i -= n0; }
  else return;
  float4 a = ((const float4*)s)[2 * i];
  float4 b = ((const float4*)s)[2 * i + 1];
  int4v o;
  o[0] = (int)pk2(a.x, a.y); o[1] = (int)pk2(a.z, a.w);
  o[2] = (int)pk2(b.x, b.y); o[3] = (int)pk2(b.z, b.w);
  ((int4v*)d)[i] = o;
}

// NT gemm with fp32 A (converted to bf16 in staging): out[m,n]=sum_k A[m,k]*W[n,k]+bias[n]
// MODE 0: fp32 out (stride ostr).  MODE 1: bf16 qryW[m][n]=v*watt[n], bf16 qryT[b][n][q]=v.
template <int MODE>
__global__ __launch_bounds__(256) void gemm_f32a_nt(
    const float* __restrict__ A, const unsigned short* __restrict__ W,
    const float* __restrict__ bias, float* __restrict__ out32, int ostr,
    unsigned short* __restrict__ ob1, unsigned short* __restrict__ ob2,
    const float* __restrict__ watt, int K) {
  __shared__ __align__(16) unsigned short As[128 * 32];
  __shared__ __align__(16) unsigned short Ws[128 * 32];
  const int tid = threadIdx.x;
  const int l = tid & 63;
  const int w = tid >> 6;
  const int bm = blockIdx.y * 128;
  const int bn = blockIdx.x * 128;
  const int wr = (w >> 1) * 64;
  const int wc = (w & 1) * 64;
  const int fr = l & 15;
  const int fq = l >> 4;
  const int srow = tid >> 1;
  const int shalf = (tid & 1) * 16;

  f32x4 acc[4][4];
#pragma unroll
  for (int i = 0; i < 4; ++i)
#pragma unroll
    for (int j = 0; j < 4; ++j)
#pragma unroll
      for (int e = 0; e < 4; ++e) acc[i][j][e] = 0.f;

  for (int k0 = 0; k0 < K; k0 += 32) {
    const float* a_src = A + (size_t)(bm + srow) * K + k0 + shalf;
    float4 f0 = *(const float4*)(a_src);
    float4 f1 = *(const float4*)(a_src + 4);
    float4 f2 = *(const float4*)(a_src + 8);
    float4 f3 = *(const float4*)(a_src + 12);
    const int4v* w_src = (const int4v*)(W + (size_t)(bn + srow) * K + k0 + shalf);
    int4v wv0 = w_src[0], wv1 = w_src[1];
    int4v aw0, aw1;
    aw0[0] = (int)pk2(f0.x, f0.y); aw0[1] = (int)pk2(f0.z, f0.w);
    aw0[2] = (int)pk2(f1.x, f1.y); aw0[3] = (int)pk2(f1.z, f1.w);
    aw1[0] = (int)pk2(f2.x, f2.y); aw1[1] = (int)pk2(f2.z, f2.w);
    aw1[2] = (int)pk2(f3.x, f3.y); aw1[3] = (int)pk2(f3.z, f3.w);
    ((int4v*)(As + srow * 32 + shalf))[0] = aw0;
    ((int4v*)(As + srow * 32 + shalf))[1] = aw1;
    ((int4v*)(Ws + srow * 32 + shalf))[0] = wv0;
    ((int4v*)(Ws + srow * 32 + shalf))[1] = wv1;
    __syncthreads();
    bf16x8 af[4], wf[4];
#pragma unroll
    for (int i = 0; i < 4; ++i)
      af[i] = *(const bf16x8*)(As + (wr + i * 16 + fr) * 32 + fq * 8);
#pragma unroll
    for (int j = 0; j < 4; ++j)
      wf[j] = *(const bf16x8*)(Ws + (wc + j * 16 + fr) * 32 + fq * 8);
#pragma unroll
    for (int i = 0; i < 4; ++i)
#pragma unroll
      for (int j = 0; j < 4; ++j)
        acc[i][j] = __builtin_amdgcn_mfma_f32_16x16x32_bf16(af[i], wf[j], acc[i][j], 0, 0, 0);
    __syncthreads();
  }
#pragma unroll
  for (int i = 0; i < 4; ++i) {
#pragma unroll
    for (int j = 0; j < 4; ++j) {
      int n = bn + wc + j * 16 + fr;
      float bb = bias[n];
      if constexpr (MODE == 0) {
#pragma unroll
        for (int r = 0; r < 4; ++r) {
          int m = bm + wr + i * 16 + fq * 4 + r;
          out32[(size_t)m * ostr + n] = acc[i][j][r] + bb;
        }
      } else {
        float wv = watt[n];
        ushort4 t4;
#pragma unroll
        for (int r = 0; r < 4; ++r) {
          int m = bm + wr + i * 16 + fq * 4 + r;
          float v = acc[i][j][r] + bb;
          ob1[(size_t)m * H_ + n] = f2bf(v * wv);
          (&t4.x)[r] = f2bf(v);
        }
        int bidx = bm >> 7;
        int q0 = wr + i * 16 + fq * 4;
        *(ushort4*)(ob2 + ((size_t)bidx * H_ + n) * Q_ + q0) = t4;
      }
    }
  }
}

// Fused attention: block = 64 ctx rows, 4 waves, MFMA 16x16x32 bf16.
__global__ __launch_bounds__(256) void attn3_kernel(
    float* __restrict__ out, const unsigned short* __restrict__ qryW,
    const unsigned short* __restrict__ qryT, const float* __restrict__ b_att,
    const float* __restrict__ cmask, const float* __restrict__ qmask,
    float* __restrict__ q2c) {
  __shared__ __align__(16) unsigned char smem[16384 + 65536];
  unsigned char* r1 = smem + 16384;
  const int tid = threadIdx.x;
  const int lane = tid & 63;
  const int w = tid >> 6;
  const int fr = lane & 15;
  const int g = lane >> 4;
  const int bc0 = blockIdx.x * 64;
  const int b = bc0 >> 10;
  const int wm = w * 16;

  const int ar = tid >> 2, ak = (tid & 3) * 16;
  const int br = tid >> 1, bk = (tid & 1) * 4;
  const float* aSrcBase = out + (size_t)(bc0 + ar) * OSTR + ak;
  const unsigned short* bSrcBase = qryW + (size_t)(b * Q_ + br) * H_ + bk * 8;
  const int pr = tid >> 1, pc16 = (tid & 1) * 8;

  f32x4 acc[8];
#pragma unroll
  for (int nf = 0; nf < 8; ++nf)
#pragma unroll
    for (int e = 0; e < 4; ++e) acc[nf][e] = 0.f;

  float4 a0, a1, a2, a3;
  int4v bv0, bv1, bv2, bv3;
  auto LOAD_AB = [&](int t) {
    const float* s = aSrcBase + t * 64;
    a0 = *(const float4*)(s);      a1 = *(const float4*)(s + 4);
    a2 = *(const float4*)(s + 8);  a3 = *(const float4*)(s + 12);
    const int4v* bs = (const int4v*)(bSrcBase + t * 64);
    bv0 = bs[0]; bv1 = bs[1]; bv2 = bs[2]; bv3 = bs[3];
  };
  auto WRITE_AB = [&](int buf) {
    unsigned char* bA = r1 + buf * 24576;
    unsigned char* bB = bA + 8192;
    int4v w0, w1;
    w0[0] = (int)pk2(a0.x, a0.y); w0[1] = (int)pk2(a0.z, a0.w);
    w0[2] = (int)pk2(a1.x, a1.y); w0[3] = (int)pk2(a1.z, a1.w);
    w1[0] = (int)pk2(a2.x, a2.y); w1[1] = (int)pk2(a2.z, a2.w);
    w1[2] = (int)pk2(a3.x, a3.y); w1[3] = (int)pk2(a3.z, a3.w);
    const int c16a = (tid & 3) * 2;
    *(int4v*)(bA + ar * 128 + ((c16a ^ (ar & 7)) << 4)) = w0;
    *(int4v*)(bA + ar * 128 + (((c16a + 1) ^ (ar & 7)) << 4)) = w1;
    *(int4v*)(bB + br * 128 + (((bk + 0) ^ (br & 7)) << 4)) = bv0;
    *(int4v*)(bB + br * 128 + (((bk + 1) ^ (br & 7)) << 4)) = bv1;
    *(int4v*)(bB + br * 128 + (((bk + 2) ^ (br & 7)) << 4)) = bv2;
    *(int4v*)(bB + br * 128 + (((bk + 3) ^ (br & 7)) << 4)) = bv3;
  };

  LOAD_AB(0);
  WRITE_AB(0);
  __syncthreads();

  for (int t = 0; t < 12; ++t) {
    const int cur = t & 1;
    if (t < 11) LOAD_AB(t + 1);
    const unsigned char* bA = r1 + cur * 24576;
    const unsigned char* bB = bA + 8192;
    const int rowa = wm + fr;
#pragma unroll
    for (int kk = 0; kk < 2; ++kk) {
      bf16x8 af = *(const bf16x8*)(bA + rowa * 128 + (((kk * 4 + g) ^ (rowa & 7)) << 4));
#pragma unroll
      for (int nf = 0; nf < 8; ++nf) {
        const int rq = nf * 16 + fr;
        bf16x8 bf = *(const bf16x8*)(bB + rq * 128 + (((kk * 4 + g) ^ (rq & 7)) << 4));
        acc[nf] = __builtin_amdgcn_mfma_f32_16x16x32_bf16(af, bf, acc[nf], 0, 0, 0);
      }
    }
    if (t < 11) WRITE_AB(cur ^ 1);
    __syncthreads();
  }

  int4v pv[8];
  auto PV_LOAD = [&](int ch) {
    const int4v* s = (const int4v*)(qryT + ((size_t)b * H_ + ch * 128 + pr) * Q_ + pc16 * 8);
#pragma unroll
    for (int i = 0; i < 8; ++i) pv[i] = s[i];
  };
  auto PV_WRITE = [&](int buf) {
    unsigned char* bP = r1 + buf * 32768;
#pragma unroll
    for (int i = 0; i < 8; ++i)
      *(int4v*)(bP + pr * 256 + (((pc16 + i) ^ (pr & 7)) << 4)) = pv[i];
  };

  PV_LOAD(0);

  {
    const float batt = b_att[0];
    float qm[8];
#pragma unroll
    for (int nf = 0; nf < 8; ++nf) qm[nf] = qmask[b * Q_ + nf * 16 + fr];
#pragma unroll
    for (int r = 0; r < 4; ++r) {
      float mx = acc[0][r];
#pragma unroll
      for (int nf = 1; nf < 8; ++nf) mx = fmaxf(mx, acc[nf][r]);
      mx = fmaxf(mx, __shfl_xor(mx, 1));
      mx = fmaxf(mx, __shfl_xor(mx, 2));
      mx = fmaxf(mx, __shfl_xor(mx, 4));
      mx = fmaxf(mx, __shfl_xor(mx, 8));
      float e[8], s = 0.f;
#pragma unroll
      for (int nf = 0; nf < 8; ++nf) { e[nf] = __expf(acc[nf][r] - mx); s += e[nf]; }
      s += __shfl_xor(s, 1); s += __shfl_xor(s, 2);
      s += __shfl_xor(s, 4); s += __shfl_xor(s, 8);
      const int rowl = wm + g * 4 + r;
      if (fr == 0) q2c[bc0 + rowl] = mx + batt;
      const float inv = cmask[bc0 + rowl] / s;
#pragma unroll
      for (int nf = 0; nf < 8; ++nf) {
        float al = e[nf] * inv * qm[nf];
        int byo = rowl * 256 + (nf * 16 + fr) * 2;
        byo ^= (rowl & 7) << 4;
        *(unsigned short*)(smem + byo) = f2bf(al);
      }
    }
  }
  PV_WRITE(0);
  __syncthreads();

  bf16x8 paf[4];
  const int rowa2 = wm + fr;
#pragma unroll
  for (int kk = 0; kk < 4; ++kk)
    paf[kk] = *(const bf16x8*)(smem + rowa2 * 256 + (((kk * 4 + g) ^ (rowa2 & 7)) << 4));

  for (int ch = 0; ch < 6; ++ch) {
    const int cur = ch & 1;
    if (ch < 5) PV_LOAD(ch + 1);
    f32x4 pacc[8];
#pragma unroll
    for (int pn = 0; pn < 8; ++pn)
#pragma unroll
      for (int e = 0; e < 4; ++e) pacc[pn][e] = 0.f;
    const unsigned char* bP = r1 + cur * 32768;
#pragma unroll
    for (int pn = 0; pn < 8; ++pn) {
      const int rp = pn * 16 + fr;
#pragma unroll
      for (int kk = 0; kk < 4; ++kk) {
        bf16x8 bf = *(const bf16x8*)(bP + rp * 256 + (((kk * 4 + g) ^ (rp & 7)) << 4));
        pacc[pn] = __builtin_amdgcn_mfma_f32_16x16x32_bf16(paf[kk], bf, pacc[pn], 0, 0, 0);
      }
    }
    const int p0 = ch * 128;
#pragma unroll
    for (int pn = 0; pn < 8; ++pn) {
      const int p = p0 + pn * 16 + fr;
#pragma unroll
      for (int r = 0; r < 4; ++r) {
        const size_t rowg = (size_t)(bc0 + wm + g * 4 + r) * OSTR;
        float av = pacc[pn][r];
        float cx = out[rowg + p];
        out[rowg + H_ + p] = av;
        out[rowg + 2 * H_ + p] = cx * av;
      }
    }
    if (ch < 5) PV_WRITE(cur ^ 1);
    __syncthreads();
  }
}

// beta softmax + bvec + d-write fused; grid B*12 (64-p chunks), 256 threads
__global__ __launch_bounds__(256) void beta3_kernel(
    float* __restrict__ out, const float* __restrict__ q2c,
    const float* __restrict__ cmask) {
  __shared__ float sh[C_];
  __shared__ float red[256];
  __shared__ float bb[64];
  const int tid = threadIdx.x;
  const int b = blockIdx.x / 12;
  const int p0 = (blockIdx.x % 12) * 64;
  float v[4];
  float lm = -1e30f;
#pragma unroll
  for (int i = 0; i < 4; ++i) {
    v[i] = q2c[b * C_ + i * 256 + tid];
    lm = fmaxf(lm, v[i]);
  }
  red[tid] = lm;
  __syncthreads();
  for (int off = 128; off > 0; off >>= 1) {
    if (tid < off) red[tid] = fmaxf(red[tid], red[tid + off]);
    __syncthreads();
  }
  const float m = red[0];
  __syncthreads();
  float ls = 0.f;
#pragma unroll
  for (int i = 0; i < 4; ++i) {
    float e = __expf(v[i] - m);
    sh[i * 256 + tid] = e * cmask[b * C_ + i * 256 + tid];
    ls += e;
  }
  red[tid] = ls;
  __syncthreads();
  for (int off = 128; off > 0; off >>= 1) {
    if (tid < off) red[tid] += red[tid + off];
    __syncthreads();
  }
  const float denom = red[0];
  const int pp = tid & 63;
  const int cg = tid >> 6;
  const float* base = out + ((size_t)b * C_ + cg) * OSTR + p0 + pp;
  float acc = 0.f;
#pragma unroll 4
  for (int c = cg; c < C_; c += 4) {
    acc += sh[c] * (*base);
    base += 4 * OSTR;
  }
  __syncthreads();
  red[tid] = acc;
  __syncthreads();
  if (tid < 64)
    bb[tid] = (red[tid] + red[tid + 64] + red[tid + 128] + red[tid + 192]) / denom;
  __syncthreads();
  // pass 2: d[c, p0+pp] = ctx * bvec (ctx lines are L2-warm from pass 1)
  const float bv = bb[pp];
  float* b2 = out + ((size_t)b * C_ + cg) * OSTR + p0 + pp;
#pragma unroll 4
  for (int c = cg; c < C_; c += 4) {
    b2[3 * H_] = b2[0] * bv;
    b2 += 4 * OSTR;
  }
}

extern "C" void kernel_launch(void* const* d_in, const int* in_sizes, int n_in,
                              void* d_out, int out_size, void* d_ws, size_t ws_size,
                              hipStream_t stream) {
  const float* context = (const float*)d_in[0];
  const float* cmask   = (const float*)d_in[1];
  const float* query   = (const float*)d_in[2];
  const float* qmask   = (const float*)d_in[3];
  const float* Wc      = (const float*)d_in[4];
  const float* bc      = (const float*)d_in[5];
  const float* Wq      = (const float*)d_in[6];
  const float* bq      = (const float*)d_in[7];
  const float* w_att   = (const float*)d_in[8];
  const float* b_att   = (const float*)d_in[9];
  float* out = (float*)d_out;

  unsigned short* ws_Wcb  = (unsigned short*)d_ws;             // H*H
  unsigned short* ws_Wqb  = ws_Wcb + (size_t)H_ * H_;          // H*H
  unsigned short* ws_qryW = ws_Wqb + (size_t)H_ * H_;          // B*Q*H
  unsigned short* ws_qryT = ws_qryW + (size_t)B_ * Q_ * H_;    // B*H*Q
  float* ws_q2c = (float*)(ws_qryT + (size_t)B_ * H_ * Q_);    // B*C

  // weight conversions (one launch)
  {
    int n0 = H_ * H_ / 8, n1 = H_ * H_ / 8;
    f2bf2_kernel<<<(n0 + n1 + 255) / 256, 256, 0, stream>>>(Wc, ws_Wcb, n0, Wq, ws_Wqb, n1);
  }
  // qry projection -> qryW (w_att folded) + qryT, both bf16 (fp32 A in-kernel cvt)
  gemm_f32a_nt<1><<<dim3(H_ / 128, (B_ * Q_) / 128), 256, 0, stream>>>(
      query, ws_Wqb, bq, nullptr, 0, ws_qryW, ws_qryT, w_att, H_);
  // ctx projection -> out cols [0,H), fp32, stride 4H (fp32 A in-kernel cvt)
  gemm_f32a_nt<0><<<dim3(H_ / 128, (B_ * C_) / 128), 256, 0, stream>>>(
      context, ws_Wcb, bc, out, OSTR, nullptr, nullptr, nullptr, H_);
  // fused attention: a, c, q2c
  attn3_kernel<<<(B_ * C_) / 64, 256, 0, stream>>>(out, ws_qryW, ws_qryT, b_att,
                                                   cmask, qmask, ws_q2c);
  // beta softmax + bvec + d
  beta3_kernel<<<B_ * 12, 256, 0, stream>>>(out, ws_q2c, cmask);
}

// Round 5
// 182.897 us; speedup vs baseline: 1.0132x; 1.0132x over previous
//
#include <hip/hip_runtime.h>
#include <cstdint>

#define B_ 16
#define C_ 1024
#define Q_ 128
#define H_ 768
#define OSTR (4 * H_)  // 3072

typedef __attribute__((ext_vector_type(8))) short bf16x8;
typedef __attribute__((ext_vector_type(4))) float f32x4;
typedef __attribute__((ext_vector_type(4))) int int4v;

__device__ __forceinline__ unsigned short f2bf(float x) {
  union { float f; unsigned u; } v; v.f = x;
  unsigned r = v.u + 0x7FFFu + ((v.u >> 16) & 1u);
  return (unsigned short)(r >> 16);
}
__device__ __forceinline__ unsigned pk2(float a, float b) {
  return (unsigned)f2bf(a) | ((unsigned)f2bf(b) << 16);
}

// two-segment fp32 -> bf16 (Wc, Wq)
__global__ __launch_bounds__(256) void f2bf2_kernel(
    const float* __restrict__ s0, unsigned short* __restrict__ d0, int n0,
    const float* __restrict__ s1, unsigned short* __restrict__ d1, int n1) {
  int i = blockIdx.x * 256 + threadIdx.x;
  const float* s;
  unsigned short* d;
  if (i < n0) { s = s0; d = d0; }
  else if (i < n0 + n1) { s = s1; d = d1; i -= n0; }
  else return;
  float4 a = ((const float4*)s)[2 * i];
  float4 b = ((const float4*)s)[2 * i + 1];
  int4v o;
  o[0] = (int)pk2(a.x, a.y); o[1] = (int)pk2(a.z, a.w);
  o[2] = (int)pk2(b.x, b.y); o[3] = (int)pk2(b.z, b.w);
  ((int4v*)d)[i] = o;
}

// NT gemm, fp32 A converted in staging. 128x128 tile, 4 waves, flat grid with
// bijective XCD-chunked swizzle (qchunk = nwg/8 blocks per XCD).
// MODE 0: fp32 out (stride ostr).  MODE 1: bf16 qryW[m][n]=v*watt[n], qryT[b][n][q]=v.
template <int MODE>
__global__ __launch_bounds__(256) void gemm_f32a_nt(
    const float* __restrict__ A, const unsigned short* __restrict__ W,
    const float* __restrict__ bias, float* __restrict__ out32, int ostr,
    unsigned short* __restrict__ ob1, unsigned short* __restrict__ ob2,
    const float* __restrict__ watt, int K, int qchunk) {
  __shared__ __align__(16) unsigned short As[128 * 32];
  __shared__ __align__(16) unsigned short Ws[128 * 32];
  const int tid = threadIdx.x;
  const int l = tid & 63;
  const int w = tid >> 6;
  const int L = blockIdx.x;
  const int orig = (L & 7) * qchunk + (L >> 3);  // XCD gets contiguous m-panels
  const int bm = (orig / 6) * 128;
  const int bn = (orig % 6) * 128;
  const int wr = (w >> 1) * 64;
  const int wc = (w & 1) * 64;
  const int fr = l & 15;
  const int fq = l >> 4;
  const int srow = tid >> 1;
  const int shalf = (tid & 1) * 16;

  f32x4 acc[4][4];
#pragma unroll
  for (int i = 0; i < 4; ++i)
#pragma unroll
    for (int j = 0; j < 4; ++j)
#pragma unroll
      for (int e = 0; e < 4; ++e) acc[i][j][e] = 0.f;

  for (int k0 = 0; k0 < K; k0 += 32) {
    const float* a_src = A + (size_t)(bm + srow) * K + k0 + shalf;
    float4 f0 = *(const float4*)(a_src);
    float4 f1 = *(const float4*)(a_src + 4);
    float4 f2 = *(const float4*)(a_src + 8);
    float4 f3 = *(const float4*)(a_src + 12);
    const int4v* w_src = (const int4v*)(W + (size_t)(bn + srow) * K + k0 + shalf);
    int4v wv0 = w_src[0], wv1 = w_src[1];
    int4v aw0, aw1;
    aw0[0] = (int)pk2(f0.x, f0.y); aw0[1] = (int)pk2(f0.z, f0.w);
    aw0[2] = (int)pk2(f1.x, f1.y); aw0[3] = (int)pk2(f1.z, f1.w);
    aw1[0] = (int)pk2(f2.x, f2.y); aw1[1] = (int)pk2(f2.z, f2.w);
    aw1[2] = (int)pk2(f3.x, f3.y); aw1[3] = (int)pk2(f3.z, f3.w);
    ((int4v*)(As + srow * 32 + shalf))[0] = aw0;
    ((int4v*)(As + srow * 32 + shalf))[1] = aw1;
    ((int4v*)(Ws + srow * 32 + shalf))[0] = wv0;
    ((int4v*)(Ws + srow * 32 + shalf))[1] = wv1;
    __syncthreads();
    bf16x8 af[4], wf[4];
#pragma unroll
    for (int i = 0; i < 4; ++i)
      af[i] = *(const bf16x8*)(As + (wr + i * 16 + fr) * 32 + fq * 8);
#pragma unroll
    for (int j = 0; j < 4; ++j)
      wf[j] = *(const bf16x8*)(Ws + (wc + j * 16 + fr) * 32 + fq * 8);
#pragma unroll
    for (int i = 0; i < 4; ++i)
#pragma unroll
      for (int j = 0; j < 4; ++j)
        acc[i][j] = __builtin_amdgcn_mfma_f32_16x16x32_bf16(af[i], wf[j], acc[i][j], 0, 0, 0);
    __syncthreads();
  }
#pragma unroll
  for (int i = 0; i < 4; ++i) {
#pragma unroll
    for (int j = 0; j < 4; ++j) {
      int n = bn + wc + j * 16 + fr;
      float bb = bias[n];
      if constexpr (MODE == 0) {
#pragma unroll
        for (int r = 0; r < 4; ++r) {
          int m = bm + wr + i * 16 + fq * 4 + r;
          out32[(size_t)m * ostr + n] = acc[i][j][r] + bb;
        }
      } else {
        float wv = watt[n];
        ushort4 t4;
#pragma unroll
        for (int r = 0; r < 4; ++r) {
          int m = bm + wr + i * 16 + fq * 4 + r;
          float v = acc[i][j][r] + bb;
          ob1[(size_t)m * H_ + n] = f2bf(v * wv);
          (&t4.x)[r] = f2bf(v);
        }
        int bidx = bm >> 7;
        int q0 = wr + i * 16 + fq * 4;
        *(ushort4*)(ob2 + ((size_t)bidx * H_ + n) * Q_ + q0) = t4;
      }
    }
  }
}

// Fused attention: block = 32 ctx rows, 4 waves = (row-tile, q-half), grid 512.
// LDS 72.5 KB -> 2 blocks/CU. Split softmax across wave pairs.
__global__ __launch_bounds__(256) void attn4_kernel(
    float* __restrict__ out, const unsigned short* __restrict__ qryW,
    const unsigned short* __restrict__ qryT, const float* __restrict__ b_att,
    const float* __restrict__ cmask, const float* __restrict__ qmask,
    float* __restrict__ q2c) {
  __shared__ __align__(16) unsigned char smem[8192 + 65536];
  __shared__ float pmS[2][32];
  __shared__ float psS[2][32];
  unsigned char* r1 = smem + 8192;  // sim bufs: j*20480 (A 4K, B 16K); PV bufs: j*32768
  const int tid = threadIdx.x;
  const int lane = tid & 63;
  const int w = tid >> 6;
  const int fr = lane & 15;
  const int g = lane >> 4;
  const int rt = w & 1;   // row-tile (16 rows)
  const int qh = w >> 1;  // q-half (64 q) / p-half in PV
  const int L = blockIdx.x;
  const int orig = (L & 7) * 64 + (L >> 3);  // XCD-chunked: 2 batches per XCD
  const int bc0 = orig * 32;
  const int b = bc0 >> 10;

  const int ar = tid >> 3, ak = (tid & 7) * 8;  // A: 32 rows x 64 k fp32
  const int br = tid >> 1, bk = (tid & 1) * 4;  // B: 128 q x 64 k bf16
  const float* aSrcBase = out + (size_t)(bc0 + ar) * OSTR + ak;
  const unsigned short* bSrcBase = qryW + (size_t)(b * Q_ + br) * H_ + bk * 8;
  const int pr = tid >> 1, pc16 = (tid & 1) * 8;  // PV: 128 p x 128 q bf16

  f32x4 acc[4];
#pragma unroll
  for (int nf = 0; nf < 4; ++nf)
#pragma unroll
    for (int e = 0; e < 4; ++e) acc[nf][e] = 0.f;

  float4 a0, a1;
  int4v bv0, bv1, bv2, bv3;
  auto LOAD_AB = [&](int t) {
    const float* s = aSrcBase + t * 64;
    a0 = *(const float4*)(s);
    a1 = *(const float4*)(s + 4);
    const int4v* bs = (const int4v*)(bSrcBase + t * 64);
    bv0 = bs[0]; bv1 = bs[1]; bv2 = bs[2]; bv3 = bs[3];
  };
  auto WRITE_AB = [&](int buf) {
    unsigned char* bA = r1 + buf * 20480;
    unsigned char* bB = bA + 4096;
    int4v w0;
    w0[0] = (int)pk2(a0.x, a0.y); w0[1] = (int)pk2(a0.z, a0.w);
    w0[2] = (int)pk2(a1.x, a1.y); w0[3] = (int)pk2(a1.z, a1.w);
    const int ck = tid & 7;
    *(int4v*)(bA + ar * 128 + ((ck ^ (ar & 7)) << 4)) = w0;
    *(int4v*)(bB + br * 128 + (((bk + 0) ^ (br & 7)) << 4)) = bv0;
    *(int4v*)(bB + br * 128 + (((bk + 1) ^ (br & 7)) << 4)) = bv1;
    *(int4v*)(bB + br * 128 + (((bk + 2) ^ (br & 7)) << 4)) = bv2;
    *(int4v*)(bB + br * 128 + (((bk + 3) ^ (br & 7)) << 4)) = bv3;
  };

  LOAD_AB(0);
  WRITE_AB(0);
  __syncthreads();

  // ---- sim: acc[nf] = sum_k ctx[rt*16+..][k] * qryW[q=qh*64+nf*16+fr][k] ----
  for (int t = 0; t < 12; ++t) {
    const int cur = t & 1;
    if (t < 11) LOAD_AB(t + 1);
    const unsigned char* bA = r1 + cur * 20480;
    const unsigned char* bB = bA + 4096;
    const int rowa = rt * 16 + fr;
#pragma unroll
    for (int kk = 0; kk < 2; ++kk) {
      bf16x8 af = *(const bf16x8*)(bA + rowa * 128 + (((kk * 4 + g) ^ (rowa & 7)) << 4));
#pragma unroll
      for (int nf = 0; nf < 4; ++nf) {
        const int rq = qh * 64 + nf * 16 + fr;
        bf16x8 bf = *(const bf16x8*)(bB + rq * 128 + (((kk * 4 + g) ^ (rq & 7)) << 4));
        acc[nf] = __builtin_amdgcn_mfma_f32_16x16x32_bf16(af, bf, acc[nf], 0, 0, 0);
      }
    }
    if (t < 11) WRITE_AB(cur ^ 1);
    __syncthreads();
  }

  int4v pv[8];
  auto PV_LOAD = [&](int ch) {
    const int4v* s = (const int4v*)(qryT + ((size_t)b * H_ + ch * 128 + pr) * Q_ + pc16 * 8);
#pragma unroll
    for (int i = 0; i < 8; ++i) pv[i] = s[i];
  };
  auto PV_WRITE = [&](int buf) {
    unsigned char* bP = r1 + buf * 32768;
#pragma unroll
    for (int i = 0; i < 8; ++i)
      *(int4v*)(bP + pr * 256 + (((pc16 + i) ^ (pr & 7)) << 4)) = pv[i];
  };

  // ---- split softmax: per-wave partials, cross-wave combine ----
  float mxr[4], er[4][4];
#pragma unroll
  for (int r = 0; r < 4; ++r) {
    float mx = acc[0][r];
#pragma unroll
    for (int nf = 1; nf < 4; ++nf) mx = fmaxf(mx, acc[nf][r]);
    mx = fmaxf(mx, __shfl_xor(mx, 1));
    mx = fmaxf(mx, __shfl_xor(mx, 2));
    mx = fmaxf(mx, __shfl_xor(mx, 4));
    mx = fmaxf(mx, __shfl_xor(mx, 8));
    float s = 0.f;
#pragma unroll
    for (int nf = 0; nf < 4; ++nf) { er[r][nf] = __expf(acc[nf][r] - mx); s += er[r][nf]; }
    s += __shfl_xor(s, 1); s += __shfl_xor(s, 2);
    s += __shfl_xor(s, 4); s += __shfl_xor(s, 8);
    mxr[r] = mx;
    const int rowl = rt * 16 + g * 4 + r;
    if (fr == 0) { pmS[qh][rowl] = mx; psS[qh][rowl] = s; }
  }
  __syncthreads();
  PV_LOAD(0);  // overlap HBM latency with the combine
  {
    const float batt = b_att[0];
    float qm[4];
#pragma unroll
    for (int nf = 0; nf < 4; ++nf) qm[nf] = qmask[b * Q_ + qh * 64 + nf * 16 + fr];
#pragma unroll
    for (int r = 0; r < 4; ++r) {
      const int rowl = rt * 16 + g * 4 + r;
      float m0 = pmS[0][rowl], m1 = pmS[1][rowl];
      float M = fmaxf(m0, m1);
      float S = psS[0][rowl] * __expf(m0 - M) + psS[1][rowl] * __expf(m1 - M);
      if (qh == 0 && fr == 0) q2c[bc0 + rowl] = M + batt;
      float scale = __expf(mxr[r] - M) * cmask[bc0 + rowl] / S;
#pragma unroll
      for (int nf = 0; nf < 4; ++nf) {
        float al = er[r][nf] * scale * qm[nf];
        int byo = rowl * 256 + (qh * 64 + nf * 16 + fr) * 2;
        byo ^= (rowl & 7) << 4;
        *(unsigned short*)(smem + byo) = f2bf(al);
      }
    }
  }
  PV_WRITE(0);
  __syncthreads();

  // ---- PV: a[row][p] = sum_q alpha[row][q] * qryT[p][q] ----
  bf16x8 paf[4];
  const int rowa2 = rt * 16 + fr;
#pragma unroll
  for (int kk = 0; kk < 4; ++kk)
    paf[kk] = *(const bf16x8*)(smem + rowa2 * 256 + (((kk * 4 + g) ^ (rowa2 & 7)) << 4));

  for (int ch = 0; ch < 6; ++ch) {
    const int cur = ch & 1;
    if (ch < 5) PV_LOAD(ch + 1);
    f32x4 pacc[4];
#pragma unroll
    for (int pn = 0; pn < 4; ++pn)
#pragma unroll
      for (int e = 0; e < 4; ++e) pacc[pn][e] = 0.f;
    const unsigned char* bP = r1 + cur * 32768;
#pragma unroll
    for (int pn = 0; pn < 4; ++pn) {
      const int rp = qh * 64 + pn * 16 + fr;
#pragma unroll
      for (int kk = 0; kk < 4; ++kk) {
        bf16x8 bf = *(const bf16x8*)(bP + rp * 256 + (((kk * 4 + g) ^ (rp & 7)) << 4));
        pacc[pn] = __builtin_amdgcn_mfma_f32_16x16x32_bf16(paf[kk], bf, pacc[pn], 0, 0, 0);
      }
    }
    const int p0 = ch * 128;
#pragma unroll
    for (int pn = 0; pn < 4; ++pn) {
      const int p = p0 + qh * 64 + pn * 16 + fr;
#pragma unroll
      for (int r = 0; r < 4; ++r) {
        const size_t rowg = (size_t)(bc0 + rt * 16 + g * 4 + r) * OSTR;
        float av = pacc[pn][r];
        float cx = out[rowg + p];
        out[rowg + H_ + p] = av;
        out[rowg + 2 * H_ + p] = cx * av;
      }
    }
    if (ch < 5) PV_WRITE(cur ^ 1);
    __syncthreads();
  }
}

// beta softmax + bvec + d-write fused; grid B*12 (64-p chunks), 256 threads
__global__ __launch_bounds__(256) void beta3_kernel(
    float* __restrict__ out, const float* __restrict__ q2c,
    const float* __restrict__ cmask) {
  __shared__ float sh[C_];
  __shared__ float red[256];
  __shared__ float bb[64];
  const int tid = threadIdx.x;
  const int b = blockIdx.x / 12;
  const int p0 = (blockIdx.x % 12) * 64;
  float v[4];
  float lm = -1e30f;
#pragma unroll
  for (int i = 0; i < 4; ++i) {
    v[i] = q2c[b * C_ + i * 256 + tid];
    lm = fmaxf(lm, v[i]);
  }
  red[tid] = lm;
  __syncthreads();
  for (int off = 128; off > 0; off >>= 1) {
    if (tid < off) red[tid] = fmaxf(red[tid], red[tid + off]);
    __syncthreads();
  }
  const float m = red[0];
  __syncthreads();
  float ls = 0.f;
#pragma unroll
  for (int i = 0; i < 4; ++i) {
    float e = __expf(v[i] - m);
    sh[i * 256 + tid] = e * cmask[b * C_ + i * 256 + tid];
    ls += e;
  }
  red[tid] = ls;
  __syncthreads();
  for (int off = 128; off > 0; off >>= 1) {
    if (tid < off) red[tid] += red[tid + off];
    __syncthreads();
  }
  const float denom = red[0];
  const int pp = tid & 63;
  const int cg = tid >> 6;
  const float* base = out + ((size_t)b * C_ + cg) * OSTR + p0 + pp;
  float acc = 0.f;
#pragma unroll 4
  for (int c = cg; c < C_; c += 4) {
    acc += sh[c] * (*base);
    base += 4 * OSTR;
  }
  __syncthreads();
  red[tid] = acc;
  __syncthreads();
  if (tid < 64)
    bb[tid] = (red[tid] + red[tid + 64] + red[tid + 128] + red[tid + 192]) / denom;
  __syncthreads();
  const float bv = bb[pp];
  float* b2 = out + ((size_t)b * C_ + cg) * OSTR + p0 + pp;
#pragma unroll 4
  for (int c = cg; c < C_; c += 4) {
    b2[3 * H_] = b2[0] * bv;
    b2 += 4 * OSTR;
  }
}

extern "C" void kernel_launch(void* const* d_in, const int* in_sizes, int n_in,
                              void* d_out, int out_size, void* d_ws, size_t ws_size,
                              hipStream_t stream) {
  const float* context = (const float*)d_in[0];
  const float* cmask   = (const float*)d_in[1];
  const float* query   = (const float*)d_in[2];
  const float* qmask   = (const float*)d_in[3];
  const float* Wc      = (const float*)d_in[4];
  const float* bc      = (const float*)d_in[5];
  const float* Wq      = (const float*)d_in[6];
  const float* bq      = (const float*)d_in[7];
  const float* w_att   = (const float*)d_in[8];
  const float* b_att   = (const float*)d_in[9];
  float* out = (float*)d_out;

  unsigned short* ws_Wcb  = (unsigned short*)d_ws;             // H*H
  unsigned short* ws_Wqb  = ws_Wcb + (size_t)H_ * H_;          // H*H
  unsigned short* ws_qryW = ws_Wqb + (size_t)H_ * H_;          // B*Q*H
  unsigned short* ws_qryT = ws_qryW + (size_t)B_ * Q_ * H_;    // B*H*Q
  float* ws_q2c = (float*)(ws_qryT + (size_t)B_ * H_ * Q_);    // B*C

  // weight conversions (one launch)
  {
    int n0 = H_ * H_ / 8, n1 = H_ * H_ / 8;
    f2bf2_kernel<<<(n0 + n1 + 255) / 256, 256, 0, stream>>>(Wc, ws_Wcb, n0, Wq, ws_Wqb, n1);
  }
  // qry projection -> qryW (w_att folded) + qryT, both bf16. nwg=96, qchunk=12.
  gemm_f32a_nt<1><<<96, 256, 0, stream>>>(
      query, ws_Wqb, bq, nullptr, 0, ws_qryW, ws_qryT, w_att, H_, 12);
  // ctx projection -> out cols [0,H), fp32, stride 4H. nwg=768, qchunk=96.
  gemm_f32a_nt<0><<<768, 256, 0, stream>>>(
      context, ws_Wcb, bc, out, OSTR, nullptr, nullptr, nullptr, H_, 96);
  // fused attention: a, c, q2c
  attn4_kernel<<<(B_ * C_) / 32, 256, 0, stream>>>(out, ws_qryW, ws_qryT, b_att,
                                                   cmask, qmask, ws_q2c);
  // beta softmax + bvec + d
  beta3_kernel<<<B_ * 12, 256, 0, stream>>>(out, ws_q2c, cmask);
}

// Round 6
// 181.640 us; speedup vs baseline: 1.0202x; 1.0069x over previous
//
#include <hip/hip_runtime.h>
#include <cstdint>

#define B_ 16
#define C_ 1024
#define Q_ 128
#define H_ 768
#define OSTR (4 * H_)  // 3072

typedef __attribute__((ext_vector_type(8))) short bf16x8;
typedef __attribute__((ext_vector_type(4))) float f32x4;
typedef __attribute__((ext_vector_type(4))) int int4v;

__device__ __forceinline__ unsigned short f2bf(float x) {
  union { float f; unsigned u; } v; v.f = x;
  unsigned r = v.u + 0x7FFFu + ((v.u >> 16) & 1u);
  return (unsigned short)(r >> 16);
}
__device__ __forceinline__ unsigned pk2(float a, float b) {
  return (unsigned)f2bf(a) | ((unsigned)f2bf(b) << 16);
}

// four-segment fp32 -> bf16 (context, query, Wc, Wq) in one launch
__global__ __launch_bounds__(256) void f2bf4_kernel(
    const float* __restrict__ s0, unsigned short* __restrict__ d0, int n0,
    const float* __restrict__ s1, unsigned short* __restrict__ d1, int n1,
    const float* __restrict__ s2, unsigned short* __restrict__ d2, int n2,
    const float* __restrict__ s3, unsigned short* __restrict__ d3, int n3) {
  int i = blockIdx.x * 256 + threadIdx.x;
  const float* s;
  unsigned short* d;
  if (i < n0) { s = s0; d = d0; }
  else if ((i -= n0) < n1) { s = s1; d = d1; }
  else if ((i -= n1) < n2) { s = s2; d = d2; }
  else if ((i -= n2) < n3) { s = s3; d = d3; }
  else return;
  float4 a = ((const float4*)s)[2 * i];
  float4 b = ((const float4*)s)[2 * i + 1];
  int4v o;
  o[0] = (int)pk2(a.x, a.y); o[1] = (int)pk2(a.z, a.w);
  o[2] = (int)pk2(b.x, b.y); o[3] = (int)pk2(b.z, b.w);
  ((int4v*)d)[i] = o;
}

// NT gemm, bf16 A and W, global_load_lds (width 16) staging, m97 structure.
// 128x128 tile, BK=32, 4 waves, XCD-chunked bijective swizzle.
// MODE 0: fp32 out (stride ostr) + bf16 ctx copy to ob1 [m][H].
// MODE 1: bf16 qryW[m][n]=v*watt[n] to ob1, bf16 qryT[b][n][q]=v to ob2.
template <int MODE>
__global__ __launch_bounds__(256) void gemm_glds_nt(
    const unsigned short* __restrict__ A, const unsigned short* __restrict__ W,
    const float* __restrict__ bias, float* __restrict__ out32, int ostr,
    unsigned short* __restrict__ ob1, unsigned short* __restrict__ ob2,
    const float* __restrict__ watt, int K, int qchunk, int nbn) {
  __shared__ __align__(16) unsigned short As[128 * 32];
  __shared__ __align__(16) unsigned short Ws[128 * 32];
  const int tid = threadIdx.x;
  const int lane = tid & 63;
  const int w = tid >> 6;
  const int L = blockIdx.x;
  const int orig = (L & 7) * qchunk + (L >> 3);  // XCD gets contiguous m-panels
  const int bm = (orig / nbn) * 128;
  const int bn = (orig % nbn) * 128;
  const int wr = (w >> 1) * 64;
  const int wc = (w & 1) * 64;
  const int fr = lane & 15;
  const int fq = lane >> 4;

  f32x4 acc[4][4];
#pragma unroll
  for (int i = 0; i < 4; ++i)
#pragma unroll
    for (int j = 0; j < 4; ++j)
#pragma unroll
      for (int e = 0; e < 4; ++e) acc[i][j][e] = 0.f;

  // staging via global_load_lds: chunk c = r*256 + w*64 + lane; row=c>>2, sub=c&3.
  // LDS dest is wave-uniform base (lane*16 added by HW); global src is per-lane.
  auto stage = [&](const unsigned short* __restrict__ G, unsigned short* S,
                   int brow, int k0) {
#pragma unroll
    for (int r = 0; r < 2; ++r) {
      const int c = r * 256 + w * 64 + lane;
      const int row = c >> 2, sub = c & 3;
      const unsigned short* g = G + (size_t)(brow + row) * K + k0 + sub * 8;
      unsigned short* l = S + (size_t)(r * 256 + w * 64) * 8;  // wave-uniform
      __builtin_amdgcn_global_load_lds(
          (const __attribute__((address_space(1))) void*)g,
          (__attribute__((address_space(3))) void*)l, 16, 0, 0);
    }
  };

  for (int k0 = 0; k0 < K; k0 += 32) {
    stage(A, As, bm, k0);
    stage(W, Ws, bn, k0);
    __syncthreads();  // drains vmcnt -> tiles in LDS
    bf16x8 af[4], wf[4];
#pragma unroll
    for (int i = 0; i < 4; ++i)
      af[i] = *(const bf16x8*)(As + (wr + i * 16 + fr) * 32 + fq * 8);
#pragma unroll
    for (int j = 0; j < 4; ++j)
      wf[j] = *(const bf16x8*)(Ws + (wc + j * 16 + fr) * 32 + fq * 8);
#pragma unroll
    for (int i = 0; i < 4; ++i)
#pragma unroll
      for (int j = 0; j < 4; ++j)
        acc[i][j] = __builtin_amdgcn_mfma_f32_16x16x32_bf16(af[i], wf[j], acc[i][j], 0, 0, 0);
    __syncthreads();  // safe to overwrite LDS
  }

#pragma unroll
  for (int i = 0; i < 4; ++i) {
#pragma unroll
    for (int j = 0; j < 4; ++j) {
      int n = bn + wc + j * 16 + fr;
      float bb = bias[n];
      if constexpr (MODE == 0) {
#pragma unroll
        for (int r = 0; r < 4; ++r) {
          int m = bm + wr + i * 16 + fq * 4 + r;
          float v = acc[i][j][r] + bb;
          out32[(size_t)m * ostr + n] = v;
          ob1[(size_t)m * H_ + n] = f2bf(v);  // bf16 ctx for attn A-side
        }
      } else {
        float wv = watt[n];
        ushort4 t4;
#pragma unroll
        for (int r = 0; r < 4; ++r) {
          int m = bm + wr + i * 16 + fq * 4 + r;
          float v = acc[i][j][r] + bb;
          ob1[(size_t)m * H_ + n] = f2bf(v * wv);
          (&t4.x)[r] = f2bf(v);
        }
        int bidx = bm >> 7;
        int q0 = wr + i * 16 + fq * 4;
        *(ushort4*)(ob2 + ((size_t)bidx * H_ + n) * Q_ + q0) = t4;
      }
    }
  }
}

// Fused attention: block = 32 ctx rows, 4 waves = (row-tile, q-half), grid 512.
// A-side now reads bf16 ctx copy (no conversion in staging).
__global__ __launch_bounds__(256) void attn4_kernel(
    float* __restrict__ out, const unsigned short* __restrict__ ctxp,
    const unsigned short* __restrict__ qryW,
    const unsigned short* __restrict__ qryT, const float* __restrict__ b_att,
    const float* __restrict__ cmask, const float* __restrict__ qmask,
    float* __restrict__ q2c) {
  __shared__ __align__(16) unsigned char smem[8192 + 65536];
  __shared__ float pmS[2][32];
  __shared__ float psS[2][32];
  unsigned char* r1 = smem + 8192;  // sim bufs: j*20480 (A 4K, B 16K); PV bufs: j*32768
  const int tid = threadIdx.x;
  const int lane = tid & 63;
  const int w = tid >> 6;
  const int fr = lane & 15;
  const int g = lane >> 4;
  const int rt = w & 1;   // row-tile (16 rows)
  const int qh = w >> 1;  // q-half (64 q) / p-half in PV
  const int L = blockIdx.x;
  const int orig = (L & 7) * 64 + (L >> 3);  // XCD-chunked
  const int bc0 = orig * 32;
  const int b = bc0 >> 10;

  const int ar = tid >> 3, ak = (tid & 7) * 8;  // A: 32 rows x 64 k bf16, 16B/thread
  const int br = tid >> 1, bk = (tid & 1) * 4;  // B: 128 q x 64 k bf16
  const unsigned short* aSrcBase = ctxp + (size_t)(bc0 + ar) * H_ + ak;
  const unsigned short* bSrcBase = qryW + (size_t)(b * Q_ + br) * H_ + bk * 8;
  const int pr = tid >> 1, pc16 = (tid & 1) * 8;  // PV: 128 p x 128 q bf16

  f32x4 acc[4];
#pragma unroll
  for (int nf = 0; nf < 4; ++nf)
#pragma unroll
    for (int e = 0; e < 4; ++e) acc[nf][e] = 0.f;

  int4v av;
  int4v bv0, bv1, bv2, bv3;
  auto LOAD_AB = [&](int t) {
    av = *(const int4v*)(aSrcBase + t * 64);
    const int4v* bs = (const int4v*)(bSrcBase + t * 64);
    bv0 = bs[0]; bv1 = bs[1]; bv2 = bs[2]; bv3 = bs[3];
  };
  auto WRITE_AB = [&](int buf) {
    unsigned char* bA = r1 + buf * 20480;
    unsigned char* bB = bA + 4096;
    const int ck = tid & 7;
    *(int4v*)(bA + ar * 128 + ((ck ^ (ar & 7)) << 4)) = av;
    *(int4v*)(bB + br * 128 + (((bk + 0) ^ (br & 7)) << 4)) = bv0;
    *(int4v*)(bB + br * 128 + (((bk + 1) ^ (br & 7)) << 4)) = bv1;
    *(int4v*)(bB + br * 128 + (((bk + 2) ^ (br & 7)) << 4)) = bv2;
    *(int4v*)(bB + br * 128 + (((bk + 3) ^ (br & 7)) << 4)) = bv3;
  };

  LOAD_AB(0);
  WRITE_AB(0);
  __syncthreads();

  // ---- sim: acc[nf] = sum_k ctx[rt*16+..][k] * qryW[q=qh*64+nf*16+fr][k] ----
  for (int t = 0; t < 12; ++t) {
    const int cur = t & 1;
    if (t < 11) LOAD_AB(t + 1);
    const unsigned char* bA = r1 + cur * 20480;
    const unsigned char* bB = bA + 4096;
    const int rowa = rt * 16 + fr;
#pragma unroll
    for (int kk = 0; kk < 2; ++kk) {
      bf16x8 af = *(const bf16x8*)(bA + rowa * 128 + (((kk * 4 + g) ^ (rowa & 7)) << 4));
#pragma unroll
      for (int nf = 0; nf < 4; ++nf) {
        const int rq = qh * 64 + nf * 16 + fr;
        bf16x8 bf = *(const bf16x8*)(bB + rq * 128 + (((kk * 4 + g) ^ (rq & 7)) << 4));
        acc[nf] = __builtin_amdgcn_mfma_f32_16x16x32_bf16(af, bf, acc[nf], 0, 0, 0);
      }
    }
    if (t < 11) WRITE_AB(cur ^ 1);
    __syncthreads();
  }

  int4v pv[8];
  auto PV_LOAD = [&](int ch) {
    const int4v* s = (const int4v*)(qryT + ((size_t)b * H_ + ch * 128 + pr) * Q_ + pc16 * 8);
#pragma unroll
    for (int i = 0; i < 8; ++i) pv[i] = s[i];
  };
  auto PV_WRITE = [&](int buf) {
    unsigned char* bP = r1 + buf * 32768;
#pragma unroll
    for (int i = 0; i < 8; ++i)
      *(int4v*)(bP + pr * 256 + (((pc16 + i) ^ (pr & 7)) << 4)) = pv[i];
  };

  // ---- split softmax: per-wave partials, cross-wave combine ----
  float mxr[4], er[4][4];
#pragma unroll
  for (int r = 0; r < 4; ++r) {
    float mx = acc[0][r];
#pragma unroll
    for (int nf = 1; nf < 4; ++nf) mx = fmaxf(mx, acc[nf][r]);
    mx = fmaxf(mx, __shfl_xor(mx, 1));
    mx = fmaxf(mx, __shfl_xor(mx, 2));
    mx = fmaxf(mx, __shfl_xor(mx, 4));
    mx = fmaxf(mx, __shfl_xor(mx, 8));
    float s = 0.f;
#pragma unroll
    for (int nf = 0; nf < 4; ++nf) { er[r][nf] = __expf(acc[nf][r] - mx); s += er[r][nf]; }
    s += __shfl_xor(s, 1); s += __shfl_xor(s, 2);
    s += __shfl_xor(s, 4); s += __shfl_xor(s, 8);
    mxr[r] = mx;
    const int rowl = rt * 16 + g * 4 + r;
    if (fr == 0) { pmS[qh][rowl] = mx; psS[qh][rowl] = s; }
  }
  __syncthreads();
  PV_LOAD(0);  // overlap HBM latency with the combine
  {
    const float batt = b_att[0];
    float qm[4];
#pragma unroll
    for (int nf = 0; nf < 4; ++nf) qm[nf] = qmask[b * Q_ + qh * 64 + nf * 16 + fr];
#pragma unroll
    for (int r = 0; r < 4; ++r) {
      const int rowl = rt * 16 + g * 4 + r;
      float m0 = pmS[0][rowl], m1 = pmS[1][rowl];
      float M = fmaxf(m0, m1);
      float S = psS[0][rowl] * __expf(m0 - M) + psS[1][rowl] * __expf(m1 - M);
      if (qh == 0 && fr == 0) q2c[bc0 + rowl] = M + batt;
      float scale = __expf(mxr[r] - M) * cmask[bc0 + rowl] / S;
#pragma unroll
      for (int nf = 0; nf < 4; ++nf) {
        float al = er[r][nf] * scale * qm[nf];
        int byo = rowl * 256 + (qh * 64 + nf * 16 + fr) * 2;
        byo ^= (rowl & 7) << 4;
        *(unsigned short*)(smem + byo) = f2bf(al);
      }
    }
  }
  PV_WRITE(0);
  __syncthreads();

  // ---- PV: a[row][p] = sum_q alpha[row][q] * qryT[p][q] ----
  bf16x8 paf[4];
  const int rowa2 = rt * 16 + fr;
#pragma unroll
  for (int kk = 0; kk < 4; ++kk)
    paf[kk] = *(const bf16x8*)(smem + rowa2 * 256 + (((kk * 4 + g) ^ (rowa2 & 7)) << 4));

  for (int ch = 0; ch < 6; ++ch) {
    const int cur = ch & 1;
    if (ch < 5) PV_LOAD(ch + 1);
    f32x4 pacc[4];
#pragma unroll
    for (int pn = 0; pn < 4; ++pn)
#pragma unroll
      for (int e = 0; e < 4; ++e) pacc[pn][e] = 0.f;
    const unsigned char* bP = r1 + cur * 32768;
#pragma unroll
    for (int pn = 0; pn < 4; ++pn) {
      const int rp = qh * 64 + pn * 16 + fr;
#pragma unroll
      for (int kk = 0; kk < 4; ++kk) {
        bf16x8 bf = *(const bf16x8*)(bP + rp * 256 + (((kk * 4 + g) ^ (rp & 7)) << 4));
        pacc[pn] = __builtin_amdgcn_mfma_f32_16x16x32_bf16(paf[kk], bf, pacc[pn], 0, 0, 0);
      }
    }
    const int p0 = ch * 128;
#pragma unroll
    for (int pn = 0; pn < 4; ++pn) {
      const int p = p0 + qh * 64 + pn * 16 + fr;
#pragma unroll
      for (int r = 0; r < 4; ++r) {
        const size_t rowg = (size_t)(bc0 + rt * 16 + g * 4 + r) * OSTR;
        float av2 = pacc[pn][r];
        float cx = out[rowg + p];
        out[rowg + H_ + p] = av2;
        out[rowg + 2 * H_ + p] = cx * av2;
      }
    }
    if (ch < 5) PV_WRITE(cur ^ 1);
    __syncthreads();
  }
}

// beta softmax + bvec + d-write fused; grid B*12 (64-p chunks), 256 threads
__global__ __launch_bounds__(256) void beta3_kernel(
    float* __restrict__ out, const float* __restrict__ q2c,
    const float* __restrict__ cmask) {
  __shared__ float sh[C_];
  __shared__ float red[256];
  __shared__ float bb[64];
  const int tid = threadIdx.x;
  const int b = blockIdx.x / 12;
  const int p0 = (blockIdx.x % 12) * 64;
  float v[4];
  float lm = -1e30f;
#pragma unroll
  for (int i = 0; i < 4; ++i) {
    v[i] = q2c[b * C_ + i * 256 + tid];
    lm = fmaxf(lm, v[i]);
  }
  red[tid] = lm;
  __syncthreads();
  for (int off = 128; off > 0; off >>= 1) {
    if (tid < off) red[tid] = fmaxf(red[tid], red[tid + off]);
    __syncthreads();
  }
  const float m = red[0];
  __syncthreads();
  float ls = 0.f;
#pragma unroll
  for (int i = 0; i < 4; ++i) {
    float e = __expf(v[i] - m);
    sh[i * 256 + tid] = e * cmask[b * C_ + i * 256 + tid];
    ls += e;
  }
  red[tid] = ls;
  __syncthreads();
  for (int off = 128; off > 0; off >>= 1) {
    if (tid < off) red[tid] += red[tid + off];
    __syncthreads();
  }
  const float denom = red[0];
  const int pp = tid & 63;
  const int cg = tid >> 6;
  const float* base = out + ((size_t)b * C_ + cg) * OSTR + p0 + pp;
  float acc = 0.f;
#pragma unroll 4
  for (int c = cg; c < C_; c += 4) {
    acc += sh[c] * (*base);
    base += 4 * OSTR;
  }
  __syncthreads();
  red[tid] = acc;
  __syncthreads();
  if (tid < 64)
    bb[tid] = (red[tid] + red[tid + 64] + red[tid + 128] + red[tid + 192]) / denom;
  __syncthreads();
  const float bv = bb[pp];
  float* b2 = out + ((size_t)b * C_ + cg) * OSTR + p0 + pp;
#pragma unroll 4
  for (int c = cg; c < C_; c += 4) {
    b2[3 * H_] = b2[0] * bv;
    b2 += 4 * OSTR;
  }
}

extern "C" void kernel_launch(void* const* d_in, const int* in_sizes, int n_in,
                              void* d_out, int out_size, void* d_ws, size_t ws_size,
                              hipStream_t stream) {
  const float* context = (const float*)d_in[0];
  const float* cmask   = (const float*)d_in[1];
  const float* query   = (const float*)d_in[2];
  const float* qmask   = (const float*)d_in[3];
  const float* Wc      = (const float*)d_in[4];
  const float* bc      = (const float*)d_in[5];
  const float* Wq      = (const float*)d_in[6];
  const float* bq      = (const float*)d_in[7];
  const float* w_att   = (const float*)d_in[8];
  const float* b_att   = (const float*)d_in[9];
  float* out = (float*)d_out;

  unsigned short* ws_ctxb = (unsigned short*)d_ws;             // B*C*H (bf16 context)
  unsigned short* ws_qinb = ws_ctxb + (size_t)B_ * C_ * H_;    // B*Q*H (bf16 query)
  unsigned short* ws_Wcb  = ws_qinb + (size_t)B_ * Q_ * H_;    // H*H
  unsigned short* ws_Wqb  = ws_Wcb + (size_t)H_ * H_;          // H*H
  unsigned short* ws_qryW = ws_Wqb + (size_t)H_ * H_;          // B*Q*H
  unsigned short* ws_qryT = ws_qryW + (size_t)B_ * Q_ * H_;    // B*H*Q
  unsigned short* ws_ctxp = ws_qryT + (size_t)B_ * H_ * Q_;    // B*C*H (bf16 ctx proj)
  float* ws_q2c = (float*)(ws_ctxp + (size_t)B_ * C_ * H_);    // B*C

  // fp32 -> bf16 for all four inputs, one launch
  {
    const int n0 = B_ * C_ * H_ / 8;  // 1,572,864
    const int n1 = B_ * Q_ * H_ / 8;  //   196,608
    const int n2 = H_ * H_ / 8;       //    73,728
    const int n3 = n2;
    const int tot = n0 + n1 + n2 + n3;
    f2bf4_kernel<<<(tot + 255) / 256, 256, 0, stream>>>(
        context, ws_ctxb, n0, query, ws_qinb, n1, Wc, ws_Wcb, n2, Wq, ws_Wqb, n3);
  }
  // qry projection -> qryW (w_att folded) + qryT. nwg=96, qchunk=12, nbn=6.
  gemm_glds_nt<1><<<96, 256, 0, stream>>>(
      ws_qinb, ws_Wqb, bq, nullptr, 0, ws_qryW, ws_qryT, w_att, H_, 12, 6);
  // ctx projection -> out fp32 (stride 4H) + ws_ctxp bf16. nwg=768, qchunk=96.
  gemm_glds_nt<0><<<768, 256, 0, stream>>>(
      ws_ctxb, ws_Wcb, bc, out, OSTR, ws_ctxp, nullptr, nullptr, H_, 96, 6);
  // fused attention: a, c, q2c
  attn4_kernel<<<(B_ * C_) / 32, 256, 0, stream>>>(out, ws_ctxp, ws_qryW, ws_qryT,
                                                   b_att, cmask, qmask, ws_q2c);
  // beta softmax + bvec + d
  beta3_kernel<<<B_ * 12, 256, 0, stream>>>(out, ws_q2c, cmask);
}